// Round 2
// 302.506 us; speedup vs baseline: 1.1079x; 1.1079x over previous
//
#include <hip/hip_runtime.h>
#include <stdint.h>

// ---------------------------------------------------------------------------
// LongSelfAttention: x[16384,1024] -> QKV proj -> per-token 16x16 head attn
// -> O proj.
// GEMMs: 256x256 tile, BK=64, 8 waves (2Mx4N), 8-phase interleave with
// counted vmcnt (T3+T4), LDS XOR-swizzle slot^=(row>>1)&3 (T2, applied
// via pre-swizzled global source + swizzled ds_read), setprio around MFMA
// clusters (T5), XCD-swizzled 1D grid (T1). Attention unchanged.
// Workspace layout (bytes):
//   [0,            32 MiB) x_bf16           [16384][1024]
//   [32 MiB,       40 MiB) W^T bf16 x4      [4][1024][1024]  (q,k,v,o)
//   [40 MiB,      136 MiB) qkv bf16         [3][16384][1024]  (attn overwrites q)
// ---------------------------------------------------------------------------

typedef __attribute__((ext_vector_type(8))) short short8;
typedef __attribute__((ext_vector_type(4))) float floatx4;
typedef __attribute__((address_space(1))) unsigned int gu32;
typedef __attribute__((address_space(3))) unsigned int lu32;

#define HID 1024
#define MTOK 16384                 // B*L
#define WELEM (HID * HID)          // 1048576
#define XELEM (MTOK * HID)         // 16777216

#define SBAR() __builtin_amdgcn_s_barrier()
// rule #18: pin MFMA below the wait with a sched_barrier
#define WAITLGKM() do { asm volatile("s_waitcnt lgkmcnt(0)" ::: "memory"); \
                        __builtin_amdgcn_sched_barrier(0); } while (0)

__device__ __forceinline__ unsigned short f2bf(float f) {
  union { float f; uint32_t u; } v; v.f = f;
  uint32_t u = v.u;
  u += 0x7fffu + ((u >> 16) & 1u);   // round-to-nearest-even
  return (unsigned short)(u >> 16);
}

// ---- x fp32 -> bf16, vectorized -------------------------------------------
__global__ __launch_bounds__(256) void cvt_x_kernel(const float* __restrict__ x,
                                                    unsigned short* __restrict__ xb) {
  const int idx = blockIdx.x * 256 + threadIdx.x;
  float4 v = ((const float4*)x)[idx];
  ushort4 o;
  o.x = f2bf(v.x); o.y = f2bf(v.y); o.z = f2bf(v.z); o.w = f2bf(v.w);
  ((ushort4*)xb)[idx] = o;
}

// ---- W [k][n] fp32 -> W^T [n][k] bf16 via 64x64 LDS tile ------------------
__global__ __launch_bounds__(256) void cvt_w_kernel(const float* __restrict__ W0,
                                                    const float* __restrict__ W1,
                                                    const float* __restrict__ W2,
                                                    const float* __restrict__ W3,
                                                    unsigned short* __restrict__ WT) {
  const float* W = (blockIdx.z == 0) ? W0 : (blockIdx.z == 1) ? W1
                   : (blockIdx.z == 2) ? W2 : W3;
  unsigned short* out = WT + (size_t)blockIdx.z * WELEM;
  __shared__ float tile[64][65];
  const int t = threadIdx.x;
  const int n0 = blockIdx.x * 64, k0 = blockIdx.y * 64;
#pragma unroll
  for (int i = 0; i < 4; i++) {
    const int row = i * 16 + (t >> 4);     // k within tile
    const int col = (t & 15) * 4;          // n within tile
    float4 v = *(const float4*)&W[(size_t)(k0 + row) * HID + n0 + col];
    tile[row][col] = v.x; tile[row][col + 1] = v.y;
    tile[row][col + 2] = v.z; tile[row][col + 3] = v.w;
  }
  __syncthreads();
#pragma unroll
  for (int i = 0; i < 4; i++) {
    const int n = i * 16 + (t >> 4);
    const int k = (t & 15) * 4;
    ushort4 o;
    o.x = f2bf(tile[k][n]);     o.y = f2bf(tile[k + 1][n]);
    o.z = f2bf(tile[k + 2][n]); o.w = f2bf(tile[k + 3][n]);
    *(ushort4*)&out[(size_t)(n0 + n) * HID + k0 + k] = o;
  }
}

// ---------------------------------------------------------------------------
// 256x256x(BK=64) NT GEMM, 4-phase-per-K-tile schedule (8 phases / 128 k).
// LDS per buffer: A 32KB (2 halves x [k-lo 8KB | k-hi 8KB]) + B 32KB.
// Swizzle: 16B slot s of row r holds logical k-chunk s ^ ((r&15)>>1 & 3).
//   - write side: gload_lds dest linear; per-lane GLOBAL source column is
//     pre-permuted with the same involution (rule #21).
//   - read side: frag slot = quad ^ ((r16>>1)&3).
// Staging rotation (per K-tile t):  P1: A1(t+1)   [idle buffer]
//                                   P2: B1(t+1)   [idle buffer]
//                                   P4: B0(t+2), A0(t+2) [live buffer; those
//                                       halves are dead after P3's reads,
//                                       which are lgkm-drained pre-barrier]
// vmcnt(4) before the tile-end barrier => tile t+1 fully landed; 2 half-tiles
// (4 load instrs) stay in flight across the barrier — never drained to 0.
// ---------------------------------------------------------------------------
template <bool QKV>
__global__ __launch_bounds__(512, 2) void gemm256(
    const unsigned short* __restrict__ A,     // [MTOK][HID] bf16
    const unsigned short* __restrict__ BTb,   // base of W^T array
    const float* __restrict__ b0, const float* __restrict__ b1,
    const float* __restrict__ b2,
    void* __restrict__ Cv)
{
  __shared__ short8 smem_[131072 / 16];      // 128 KiB
  char* smem = (char*)smem_;

  const int bid = blockIdx.x;
  const int xcd = bid & 7;
  const int j = bid >> 3;
  const int nb = j >> 3;                     // QKV: 0..11, O: 0..3
  const int mb = xcd * 8 + (j & 7);          // 0..63 (m-band per XCD)
  const int m0 = mb * 256;
  const int n0 = nb * 256;

  const unsigned short* BT = QKV ? BTb : (BTb + (size_t)3 * WELEM);

  const int t_ = threadIdx.x;
  const int wv = t_ >> 6, lane = t_ & 63;
  const int quad = lane >> 4, r16 = lane & 15;
  const int wm = wv >> 2, wn = wv & 3;

  // staging source (per-lane; k-chunk pre-permuted to compensate swizzle)
  const int srow = wv * 16 + (lane >> 2);
  const int scol = ((lane & 3) ^ ((lane >> 3) & 3)) * 8;
  const unsigned short* Ag = A  + (size_t)(m0 + srow) * HID + scol;
  const unsigned short* Bg = BT + (size_t)(n0 + srow) * HID + scol;

  // ds_read bases (swizzled): byte = base + ks*8192 + frag*1024
  const int qsw = (quad ^ ((r16 >> 1) & 3)) << 4;
  const char* Ard = smem + wm * 16384 + r16 * 64 + qsw;
  const char* Brd = smem + 32768 + (wn >> 1) * 16384 + ((wn & 1) * 64 + r16) * 64 + qsw;

  floatx4 acc[8][4] = {};

  // stage half h (rows h*128..h*128+127) of K-tile tt into buffer tt&1
  auto stageA = [&](int h, int tt) {
    const unsigned short* s = Ag + (size_t)h * 128 * HID + tt * 64;
    char* d = smem + ((tt & 1) << 16) + h * 16384 + wv * 1024;
    __builtin_amdgcn_global_load_lds((const gu32*)s,        (lu32*)d,          16, 0, 0);
    __builtin_amdgcn_global_load_lds((const gu32*)(s + 32), (lu32*)(d + 8192), 16, 0, 0);
  };
  auto stageB = [&](int h, int tt) {
    const unsigned short* s = Bg + (size_t)h * 128 * HID + tt * 64;
    char* d = smem + ((tt & 1) << 16) + 32768 + h * 16384 + wv * 1024;
    __builtin_amdgcn_global_load_lds((const gu32*)s,        (lu32*)d,          16, 0, 0);
    __builtin_amdgcn_global_load_lds((const gu32*)(s + 32), (lu32*)(d + 8192), 16, 0, 0);
  };

  // prologue: tile0 fully + B0,A0 of tile1; wait tile0 landed; barrier
  stageA(0, 0); stageA(1, 0); stageB(0, 0); stageB(1, 0);
  stageB(0, 1); stageA(0, 1);
  asm volatile("s_waitcnt vmcnt(4)" ::: "memory");
  SBAR();

  short8 a[4][2], b01[2][2], b23[2][2];
  const int NT = HID / 64;                   // 16 K-tiles

  for (int t = 0; t < NT; ++t) {
    const int bufb = (t & 1) << 16;

    // ---- phase 1: Q0 = m0-3 x n0-1 (12 ds_reads) --------------------------
#pragma unroll
    for (int ks = 0; ks < 2; ++ks) {
#pragma unroll
      for (int mi = 0; mi < 4; ++mi)
        a[mi][ks] = *(const short8*)(Ard + bufb + ks * 8192 + mi * 1024);
#pragma unroll
      for (int ni = 0; ni < 2; ++ni)
        b01[ni][ks] = *(const short8*)(Brd + bufb + ks * 8192 + ni * 1024);
    }
    if (t + 1 < NT) stageA(1, t + 1);
    SBAR(); WAITLGKM();
    __builtin_amdgcn_s_setprio(1);
#pragma unroll
    for (int ks = 0; ks < 2; ++ks)
#pragma unroll
      for (int mi = 0; mi < 4; ++mi)
#pragma unroll
        for (int ni = 0; ni < 2; ++ni)
          acc[mi][ni] = __builtin_amdgcn_mfma_f32_16x16x32_bf16(a[mi][ks], b01[ni][ks], acc[mi][ni], 0, 0, 0);
    __builtin_amdgcn_s_setprio(0);
    SBAR();

    // ---- phase 2: Q1 = m0-3 x n2-3 (4 ds_reads) ---------------------------
#pragma unroll
    for (int ks = 0; ks < 2; ++ks)
#pragma unroll
      for (int ni = 0; ni < 2; ++ni)
        b23[ni][ks] = *(const short8*)(Brd + bufb + ks * 8192 + (2 + ni) * 1024);
    if (t + 1 < NT) stageB(1, t + 1);
    SBAR(); WAITLGKM();
    __builtin_amdgcn_s_setprio(1);
#pragma unroll
    for (int ks = 0; ks < 2; ++ks)
#pragma unroll
      for (int mi = 0; mi < 4; ++mi)
#pragma unroll
        for (int ni = 0; ni < 2; ++ni)
          acc[mi][2 + ni] = __builtin_amdgcn_mfma_f32_16x16x32_bf16(a[mi][ks], b23[ni][ks], acc[mi][2 + ni], 0, 0, 0);
    __builtin_amdgcn_s_setprio(0);
    SBAR();

    // ---- phase 3: Q2 = m4-7 x n0-1 (12 ds_reads: A m4-7 + b01 re-read) ----
#pragma unroll
    for (int ks = 0; ks < 2; ++ks) {
#pragma unroll
      for (int mi = 0; mi < 4; ++mi)
        a[mi][ks] = *(const short8*)(Ard + bufb + ks * 8192 + (4 + mi) * 1024);
#pragma unroll
      for (int ni = 0; ni < 2; ++ni)
        b01[ni][ks] = *(const short8*)(Brd + bufb + ks * 8192 + ni * 1024);
    }
    SBAR(); WAITLGKM();
    __builtin_amdgcn_s_setprio(1);
#pragma unroll
    for (int ks = 0; ks < 2; ++ks)
#pragma unroll
      for (int mi = 0; mi < 4; ++mi)
#pragma unroll
        for (int ni = 0; ni < 2; ++ni)
          acc[4 + mi][ni] = __builtin_amdgcn_mfma_f32_16x16x32_bf16(a[mi][ks], b01[ni][ks], acc[4 + mi][ni], 0, 0, 0);
    __builtin_amdgcn_s_setprio(0);
    SBAR();

    // ---- phase 4: Q3 = m4-7 x n2-3 (0 ds_reads); stage freed live halves --
    if (t + 2 < NT) { stageB(0, t + 2); stageA(0, t + 2); }
    SBAR();
    __builtin_amdgcn_s_setprio(1);
#pragma unroll
    for (int ks = 0; ks < 2; ++ks)
#pragma unroll
      for (int mi = 0; mi < 4; ++mi)
#pragma unroll
        for (int ni = 0; ni < 2; ++ni)
          acc[4 + mi][2 + ni] = __builtin_amdgcn_mfma_f32_16x16x32_bf16(a[mi][ks], b23[ni][ks], acc[4 + mi][2 + ni], 0, 0, 0);
    __builtin_amdgcn_s_setprio(0);
    // counted drain: leave {B0,A0}(t+2) in flight; guarantees tile t+1 landed
    if (t + 2 < NT)      { asm volatile("s_waitcnt vmcnt(4)" ::: "memory"); }
    else if (t + 1 < NT) { asm volatile("s_waitcnt vmcnt(0)" ::: "memory"); }
    SBAR();
  }

  // epilogue: C/D layout col=lane&15, row=quad*4+reg (measured m89/m91)
  const int cb = QKV ? (n0 & 1023) : n0;
  const int zX = QKV ? (n0 >> 10) : 0;
  const float* bias = QKV ? ((zX == 0) ? b0 : ((zX == 1) ? b1 : b2)) : b0;

  float bvv[4];
#pragma unroll
  for (int ni = 0; ni < 4; ++ni) bvv[ni] = bias[cb + wn * 64 + ni * 16 + r16];

  const int row0 = m0 + wm * 128 + quad * 4;
  unsigned short* outb = (unsigned short*)Cv + (size_t)zX * XELEM;
  float* outf = (float*)Cv;
#pragma unroll
  for (int mi = 0; mi < 8; ++mi) {
#pragma unroll
    for (int rr = 0; rr < 4; ++rr) {
      const size_t roff = (size_t)(row0 + mi * 16 + rr) * HID + cb + wn * 64 + r16;
#pragma unroll
      for (int ni = 0; ni < 4; ++ni) {
        const float val = acc[mi][ni][rr] + bvv[ni];
        if constexpr (QKV) outb[roff + ni * 16] = f2bf(val);
        else               outf[roff + ni * 16] = val;
      }
    }
  }
}

// ---- per-token head attention: one wave per token, all-MFMA ---------------
__global__ __launch_bounds__(256) void attn_kernel(const unsigned short* qkv,
                                                   unsigned short* attn) {
  __shared__ unsigned short vls[4][1056];    // per wave: rows0-7 @0, rows8-15 @528
  __shared__ unsigned short pls[4][16 * 24]; // P bf16, stride 24 ushorts (48B)

  const int t = threadIdx.x;
  const int wv = t >> 6, lane = t & 63;
  const int quad = lane >> 4, r16 = lane & 15;
  const size_t base = ((size_t)blockIdx.x * 4 + wv) * HID;
  const unsigned short* qp = qkv + base;                     // q[16][64]
  const unsigned short* kp = qkv + (size_t)XELEM + base;     // k[16][64]
  const unsigned short* vp = qkv + 2 * (size_t)XELEM + base; // v[16][64]

  __builtin_amdgcn_global_load_lds((const gu32*)(vp + lane * 8),       (lu32*)&vls[wv][0],   16, 0, 0);
  __builtin_amdgcn_global_load_lds((const gu32*)(vp + 512 + lane * 8), (lu32*)&vls[wv][528], 16, 0, 0);

  short8 qf0 = *(const short8*)(qp + r16 * 64 + quad * 8);
  short8 qf1 = *(const short8*)(qp + r16 * 64 + quad * 8 + 32);
  short8 kf0 = *(const short8*)(kp + r16 * 64 + quad * 8);
  short8 kf1 = *(const short8*)(kp + r16 * 64 + quad * 8 + 32);

  floatx4 sc = {0.f, 0.f, 0.f, 0.f};
  sc = __builtin_amdgcn_mfma_f32_16x16x32_bf16(qf0, kf0, sc, 0, 0, 0);
  sc = __builtin_amdgcn_mfma_f32_16x16x32_bf16(qf1, kf1, sc, 0, 0, 0);

#pragma unroll
  for (int rr = 0; rr < 4; rr++) {
    float s = sc[rr] * 0.125f;
    float m = s;
#pragma unroll
    for (int off = 1; off < 16; off <<= 1) m = fmaxf(m, __shfl_xor(m, off));
    float ex = __expf(s - m);
    float sum = ex;
#pragma unroll
    for (int off = 1; off < 16; off <<= 1) sum += __shfl_xor(sum, off);
    pls[wv][(quad * 4 + rr) * 24 + r16] = f2bf(ex / sum);   // P[h][e]
  }

  __syncthreads();   // covers V DMA completion + cross-lane P visibility

  const short8 zero8 = {0, 0, 0, 0, 0, 0, 0, 0};
  short8 af = zero8;
  short8 bf[4] = {zero8, zero8, zero8, zero8};
  if (quad < 2) {
    af = *(const short8*)&pls[wv][r16 * 24 + quad * 8];
#pragma unroll
    for (int c = 0; c < 4; c++)
#pragma unroll
      for (int jj = 0; jj < 8; jj++)
        bf[c][jj] = (short)vls[wv][quad * 528 + jj * 64 + c * 16 + r16];
  }

  floatx4 ov[4];
#pragma unroll
  for (int c = 0; c < 4; c++) {
    floatx4 z = {0.f, 0.f, 0.f, 0.f};
    ov[c] = __builtin_amdgcn_mfma_f32_16x16x32_bf16(af, bf[c], z, 0, 0, 0);
  }

#pragma unroll
  for (int rr = 0; rr < 4; rr++)
#pragma unroll
    for (int c = 0; c < 4; c++)
      attn[base + (size_t)(quad * 4 + rr) * 64 + c * 16 + r16] = f2bf(ov[c][rr]);
}

extern "C" void kernel_launch(void* const* d_in, const int* in_sizes, int n_in,
                              void* d_out, int out_size, void* d_ws, size_t ws_size,
                              hipStream_t stream) {
  const float* x  = (const float*)d_in[0];
  const float* Wq = (const float*)d_in[1];
  const float* bq = (const float*)d_in[2];
  const float* Wk = (const float*)d_in[3];
  const float* bk = (const float*)d_in[4];
  const float* Wv = (const float*)d_in[5];
  const float* bv = (const float*)d_in[6];
  const float* Wo = (const float*)d_in[7];
  const float* bo = (const float*)d_in[8];

  char* ws = (char*)d_ws;
  unsigned short* xb  = (unsigned short*)ws;                        // 32 MiB
  unsigned short* wt  = (unsigned short*)(ws + (size_t)XELEM * 2);  // 8 MiB
  unsigned short* qkv = wt + 4 * (size_t)WELEM;                     // 96 MiB

  cvt_x_kernel<<<XELEM / 1024, 256, 0, stream>>>(x, xb);
  cvt_w_kernel<<<dim3(16, 16, 4), 256, 0, stream>>>(Wq, Wk, Wv, Wo, wt);
  gemm256<true><<<768, 512, 0, stream>>>(xb, wt, bq, bk, bv, (void*)qkv);
  attn_kernel<<<4096, 256, 0, stream>>>(qkv, qkv);  // attn overwrites q region
  gemm256<false><<<256, 512, 0, stream>>>(qkv, wt, bo, bo, bo, d_out);
}

// Round 3
// 292.582 us; speedup vs baseline: 1.1454x; 1.0339x over previous
//
#include <hip/hip_runtime.h>
#include <stdint.h>

// ---------------------------------------------------------------------------
// LongSelfAttention: x[16384,1024] -> QKV proj -> per-token 16x16 head attn
// -> O proj.
// GEMMs: 256x256 tile, BK=64, 8 waves (2Mx4N), 8-phase interleave with
// counted vmcnt (T3+T4), LDS XOR-swizzle (T2), setprio (T5), XCD swizzle (T1).
// This rev: zigzag quadrants + held b01 (no re-reads), balanced 8/4/8/4
// ds_read phases (b01-of-next-tile read in P4, gated by vmcnt(6)@P3-end),
// 1-half-tile-per-phase stage rotation, persistent QKV grid (256 blocks x 3
// output tiles, constant m-band per block, Bg += WELEM per tile).
// Workspace layout (bytes):
//   [0,            32 MiB) x_bf16           [16384][1024]
//   [32 MiB,       40 MiB) W^T bf16 x4      [4][1024][1024]  (q,k,v,o)
//   [40 MiB,      136 MiB) qkv bf16         [3][16384][1024]  (attn overwrites q)
// ---------------------------------------------------------------------------

typedef __attribute__((ext_vector_type(8))) short short8;
typedef __attribute__((ext_vector_type(4))) float floatx4;
typedef __attribute__((address_space(1))) unsigned int gu32;
typedef __attribute__((address_space(3))) unsigned int lu32;

#define HID 1024
#define MTOK 16384                 // B*L
#define WELEM (HID * HID)          // 1048576
#define XELEM (MTOK * HID)         // 16777216

#define SBAR() __builtin_amdgcn_s_barrier()
// rule #18: pin subsequent code below the wait with a sched_barrier
#define WAITLGKM() do { asm volatile("s_waitcnt lgkmcnt(0)" ::: "memory"); \
                        __builtin_amdgcn_sched_barrier(0); } while (0)
#define VMCNT(n) do { asm volatile("s_waitcnt vmcnt(" #n ")" ::: "memory"); \
                      __builtin_amdgcn_sched_barrier(0); } while (0)

__device__ __forceinline__ unsigned short f2bf(float f) {
  union { float f; uint32_t u; } v; v.f = f;
  uint32_t u = v.u;
  u += 0x7fffu + ((u >> 16) & 1u);   // round-to-nearest-even
  return (unsigned short)(u >> 16);
}

// ---- x fp32 -> bf16, vectorized -------------------------------------------
__global__ __launch_bounds__(256) void cvt_x_kernel(const float* __restrict__ x,
                                                    unsigned short* __restrict__ xb) {
  const int idx = blockIdx.x * 256 + threadIdx.x;
  float4 v = ((const float4*)x)[idx];
  ushort4 o;
  o.x = f2bf(v.x); o.y = f2bf(v.y); o.z = f2bf(v.z); o.w = f2bf(v.w);
  ((ushort4*)xb)[idx] = o;
}

// ---- W [k][n] fp32 -> W^T [n][k] bf16 via 64x64 LDS tile ------------------
__global__ __launch_bounds__(256) void cvt_w_kernel(const float* __restrict__ W0,
                                                    const float* __restrict__ W1,
                                                    const float* __restrict__ W2,
                                                    const float* __restrict__ W3,
                                                    unsigned short* __restrict__ WT) {
  const float* W = (blockIdx.z == 0) ? W0 : (blockIdx.z == 1) ? W1
                   : (blockIdx.z == 2) ? W2 : W3;
  unsigned short* out = WT + (size_t)blockIdx.z * WELEM;
  __shared__ float tile[64][65];
  const int t = threadIdx.x;
  const int n0 = blockIdx.x * 64, k0 = blockIdx.y * 64;
#pragma unroll
  for (int i = 0; i < 4; i++) {
    const int row = i * 16 + (t >> 4);     // k within tile
    const int col = (t & 15) * 4;          // n within tile
    float4 v = *(const float4*)&W[(size_t)(k0 + row) * HID + n0 + col];
    tile[row][col] = v.x; tile[row][col + 1] = v.y;
    tile[row][col + 2] = v.z; tile[row][col + 3] = v.w;
  }
  __syncthreads();
#pragma unroll
  for (int i = 0; i < 4; i++) {
    const int n = i * 16 + (t >> 4);
    const int k = (t & 15) * 4;
    ushort4 o;
    o.x = f2bf(tile[k][n]);     o.y = f2bf(tile[k + 1][n]);
    o.z = f2bf(tile[k + 2][n]); o.w = f2bf(tile[k + 3][n]);
    *(ushort4*)&out[(size_t)(n0 + n) * HID + k0 + k] = o;
  }
}

// ---------------------------------------------------------------------------
// 256x256x(BK=64) NT GEMM, 4-phase-per-K-tile (8 phases / 128 k).
// Reads: P1 A-lo(8), P2 b23(4), P3 A-hi(8), P4 b01-next(4) -- balanced.
// Stage rotation: P1 A0(t+1), P2 A1(t+1), P3 B0(t+2), P4 B1(t+2).
// Waits: vmcnt(6) @P3-end (B halves of t+1 landed for P4's reads),
//        vmcnt(4) @P4-end (A halves of t+1 landed; {B0,B1}(t+2) in flight).
// Dead-region audit: A-halves last read P3 (staged P1/P2 other buf);
// B-halves last read P2 (+cross-buffer b01n @P4 reads the OTHER buffer);
// stages into cur-buf B at P3/P4 are barrier-separated from those readers.
// Zigzag quadrants: Q0=Alo*b01, Q1=Alo*b23, Q2=Ahi*b23, Q3=Ahi*b01.
// Persistent: QKV runs R=3 output tiles per block (same m-band, Bg+=WELEM);
// next tile's prologue stages are issued before the epilogue stores.
// ---------------------------------------------------------------------------
template <bool QKV>
__global__ __launch_bounds__(512, 2) void gemm256(
    const unsigned short* __restrict__ A,     // [MTOK][HID] bf16
    const unsigned short* __restrict__ BTb,   // base of W^T array
    const float* __restrict__ b0, const float* __restrict__ b1,
    const float* __restrict__ b2,
    void* __restrict__ Cv)
{
  __shared__ short8 smem_[131072 / 16];      // 128 KiB
  char* smem = (char*)smem_;

  constexpr int R = QKV ? 3 : 1;
  const int bid = blockIdx.x;
  const int xcd = bid & 7;
  const int j = bid >> 3;                    // 0..31
  const int nb0 = j >> 3;                    // 0..3
  const int mb = xcd * 8 + (j & 7);          // 0..63 (m-band per XCD, fixed)
  const int m0 = mb * 256;
  const int cb = nb0 * 256;                  // output col base (per-matrix)

  const unsigned short* BT0 = QKV ? BTb : (BTb + (size_t)3 * WELEM);

  const int t_ = threadIdx.x;
  const int wv = t_ >> 6, lane = t_ & 63;
  const int quad = lane >> 4, r16 = lane & 15;
  const int wm = wv >> 2, wn = wv & 3;

  // staging source (per-lane; k-chunk pre-permuted to compensate swizzle)
  const int srow = wv * 16 + (lane >> 2);
  const int scol = ((lane & 3) ^ ((lane >> 3) & 3)) * 8;
  const unsigned short* Ag = A + (size_t)(m0 + srow) * HID + scol;
  const unsigned short* Bg = BT0 + (size_t)(cb + srow) * HID + scol;

  // ds_read bases (swizzled): byte = base + ks*8192 + frag*1024
  const int qsw = (quad ^ ((r16 >> 1) & 3)) << 4;
  const char* Ard = smem + wm * 16384 + r16 * 64 + qsw;
  const char* Brd = smem + 32768 + (wn >> 1) * 16384 + ((wn & 1) * 64 + r16) * 64 + qsw;

  floatx4 acc[8][4] = {};

  // stage half h of K-tile tt into buffer tt&1 (LDS dest linear, rule #21)
  auto stageA = [&](int h, int tt) {
    const unsigned short* s = Ag + (size_t)h * 128 * HID + tt * 64;
    char* d = smem + ((tt & 1) << 16) + h * 16384 + wv * 1024;
    __builtin_amdgcn_global_load_lds((const gu32*)s,        (lu32*)d,          16, 0, 0);
    __builtin_amdgcn_global_load_lds((const gu32*)(s + 32), (lu32*)(d + 8192), 16, 0, 0);
  };
  auto stageB = [&](int h, int tt) {
    const unsigned short* s = Bg + (size_t)h * 128 * HID + tt * 64;
    char* d = smem + ((tt & 1) << 16) + 32768 + h * 16384 + wv * 1024;
    __builtin_amdgcn_global_load_lds((const gu32*)s,        (lu32*)d,          16, 0, 0);
    __builtin_amdgcn_global_load_lds((const gu32*)(s + 32), (lu32*)(d + 8192), 16, 0, 0);
  };

  const int NT = HID / 64;                   // 16 K-tiles (even)

  short8 a[4][2];                            // A-lo then A-hi (reused)
  short8 b23[2][2];                          // wave n-frags 2,3 (per tile)
  short8 bA[2][2], bB[2][2];                 // b01 double-buffer across tiles

  // one K-tile: bufb = (t&1)<<16, othb = buffer of t+1; bc = b01 of t,
  // bn = b01 of t+1 (filled in P4).
  auto TILE = [&](int t, int bufb, int othb, short8 (&bc)[2][2], short8 (&bn)[2][2]) {
    // ---- P1: reads A-lo(8); stage A0(t+1); MFMA Q0 = Alo x b01 ------------
#pragma unroll
    for (int ks = 0; ks < 2; ++ks)
#pragma unroll
      for (int mi = 0; mi < 4; ++mi)
        a[mi][ks] = *(const short8*)(Ard + bufb + ks * 8192 + mi * 1024);
    if (t + 1 < NT) stageA(0, t + 1);
    SBAR(); WAITLGKM();
    __builtin_amdgcn_s_setprio(1);
#pragma unroll
    for (int ks = 0; ks < 2; ++ks)
#pragma unroll
      for (int mi = 0; mi < 4; ++mi)
#pragma unroll
        for (int ni = 0; ni < 2; ++ni)
          acc[mi][ni] = __builtin_amdgcn_mfma_f32_16x16x32_bf16(a[mi][ks], bc[ni][ks], acc[mi][ni], 0, 0, 0);
    __builtin_amdgcn_s_setprio(0);
    SBAR();

    // ---- P2: reads b23(4); stage A1(t+1); MFMA Q1 = Alo x b23 -------------
#pragma unroll
    for (int ks = 0; ks < 2; ++ks)
#pragma unroll
      for (int ni = 0; ni < 2; ++ni)
        b23[ni][ks] = *(const short8*)(Brd + bufb + ks * 8192 + (2 + ni) * 1024);
    if (t + 1 < NT) stageA(1, t + 1);
    SBAR(); WAITLGKM();
    __builtin_amdgcn_s_setprio(1);
#pragma unroll
    for (int ks = 0; ks < 2; ++ks)
#pragma unroll
      for (int mi = 0; mi < 4; ++mi)
#pragma unroll
        for (int ni = 0; ni < 2; ++ni)
          acc[mi][2 + ni] = __builtin_amdgcn_mfma_f32_16x16x32_bf16(a[mi][ks], b23[ni][ks], acc[mi][2 + ni], 0, 0, 0);
    __builtin_amdgcn_s_setprio(0);
    SBAR();

    // ---- P3: reads A-hi(8); stage B0(t+2); MFMA Q2 = Ahi x b23 ------------
#pragma unroll
    for (int ks = 0; ks < 2; ++ks)
#pragma unroll
      for (int mi = 0; mi < 4; ++mi)
        a[mi][ks] = *(const short8*)(Ard + bufb + ks * 8192 + (4 + mi) * 1024);
    if (t + 2 < NT) stageB(0, t + 2);
    SBAR(); WAITLGKM();
    __builtin_amdgcn_s_setprio(1);
#pragma unroll
    for (int ks = 0; ks < 2; ++ks)
#pragma unroll
      for (int mi = 0; mi < 4; ++mi)
#pragma unroll
        for (int ni = 0; ni < 2; ++ni)
          acc[4 + mi][2 + ni] = __builtin_amdgcn_mfma_f32_16x16x32_bf16(a[mi][ks], b23[ni][ks], acc[4 + mi][2 + ni], 0, 0, 0);
    __builtin_amdgcn_s_setprio(0);
    // gate P4's b01-next reads: retire {B0,B1}(t+1) (oldest 4 instrs)
    if (t + 2 < NT)      { VMCNT(6); }
    else if (t + 1 < NT) { VMCNT(4); }
    SBAR();

    // ---- P4: reads b01-next(4, other buf); stage B1(t+2); Q3 = Ahi x b01 --
    if (t + 1 < NT) {
#pragma unroll
      for (int ks = 0; ks < 2; ++ks)
#pragma unroll
        for (int ni = 0; ni < 2; ++ni)
          bn[ni][ks] = *(const short8*)(Brd + othb + ks * 8192 + ni * 1024);
    }
    if (t + 2 < NT) stageB(1, t + 2);
    SBAR();
    __builtin_amdgcn_s_setprio(1);
#pragma unroll
    for (int ks = 0; ks < 2; ++ks)
#pragma unroll
      for (int mi = 0; mi < 4; ++mi)
#pragma unroll
        for (int ni = 0; ni < 2; ++ni)
          acc[4 + mi][ni] = __builtin_amdgcn_mfma_f32_16x16x32_bf16(a[mi][ks], bc[ni][ks], acc[4 + mi][ni], 0, 0, 0);
    __builtin_amdgcn_s_setprio(0);
    // retire {A0,A1}(t+1); leave {B0,B1}(t+2) in flight across the boundary
    if (t + 2 < NT)      { VMCNT(4); }
    else if (t + 1 < NT) { VMCNT(0); }
    SBAR();
  };

  // prologue for output-tile 0: tile0 fully + {B0,B1}(1); leave B(1) in flight
  stageA(0, 0); stageA(1, 0); stageB(0, 0); stageB(1, 0);
  stageB(0, 1); stageB(1, 1);
  VMCNT(4);
  SBAR();
#pragma unroll
  for (int ks = 0; ks < 2; ++ks)
#pragma unroll
    for (int ni = 0; ni < 2; ++ni)
      bA[ni][ks] = *(const short8*)(Brd + ks * 8192 + ni * 1024);

  for (int r = 0; r < R; ++r) {
    for (int t = 0; t < NT; t += 2) {
      TILE(t,     0,       0x10000, bA, bB);
      TILE(t + 1, 0x10000, 0,       bB, bA);
    }

    // issue next output-tile's prologue stages before the epilogue stores
    if (r + 1 < R) {
      Bg += WELEM;                           // next weight matrix (z = r+1)
      stageA(0, 0); stageA(1, 0); stageB(0, 0); stageB(1, 0);
      stageB(0, 1); stageB(1, 1);
    }

    // epilogue: C/D layout col=lane&15, row=quad*4+reg (measured m89/m91)
    {
      const float* bias = QKV ? ((r == 0) ? b0 : ((r == 1) ? b1 : b2)) : b0;
      float bvv[4];
#pragma unroll
      for (int ni = 0; ni < 4; ++ni) bvv[ni] = bias[cb + wn * 64 + ni * 16 + r16];

      const int row0 = m0 + wm * 128 + quad * 4;
      unsigned short* outb = (unsigned short*)Cv + (size_t)r * XELEM;
      float* outf = (float*)Cv;
#pragma unroll
      for (int mi = 0; mi < 8; ++mi) {
#pragma unroll
        for (int rr = 0; rr < 4; ++rr) {
          const size_t roff = (size_t)(row0 + mi * 16 + rr) * HID + cb + wn * 64 + r16;
#pragma unroll
          for (int ni = 0; ni < 4; ++ni) {
            const float val = acc[mi][ni][rr] + bvv[ni];
            if constexpr (QKV) outb[roff + ni * 16] = f2bf(val);
            else               outf[roff + ni * 16] = val;
          }
        }
      }
    }

    if (r + 1 < R) {
      // zero acc, drain stages (+stores), re-read b01(0) for next tile
#pragma unroll
      for (int mi = 0; mi < 8; ++mi)
#pragma unroll
        for (int ni = 0; ni < 4; ++ni)
          acc[mi][ni] = floatx4{0.f, 0.f, 0.f, 0.f};
      VMCNT(0);
      SBAR();
#pragma unroll
      for (int ks = 0; ks < 2; ++ks)
#pragma unroll
        for (int ni = 0; ni < 2; ++ni)
          bA[ni][ks] = *(const short8*)(Brd + ks * 8192 + ni * 1024);
    }
  }
}

// ---- per-token head attention: one wave per token, all-MFMA ---------------
__global__ __launch_bounds__(256) void attn_kernel(const unsigned short* qkv,
                                                   unsigned short* attn) {
  __shared__ unsigned short vls[4][1056];    // per wave: rows0-7 @0, rows8-15 @528
  __shared__ unsigned short pls[4][16 * 24]; // P bf16, stride 24 ushorts (48B)

  const int t = threadIdx.x;
  const int wv = t >> 6, lane = t & 63;
  const int quad = lane >> 4, r16 = lane & 15;
  const size_t base = ((size_t)blockIdx.x * 4 + wv) * HID;
  const unsigned short* qp = qkv + base;                     // q[16][64]
  const unsigned short* kp = qkv + (size_t)XELEM + base;     // k[16][64]
  const unsigned short* vp = qkv + 2 * (size_t)XELEM + base; // v[16][64]

  __builtin_amdgcn_global_load_lds((const gu32*)(vp + lane * 8),       (lu32*)&vls[wv][0],   16, 0, 0);
  __builtin_amdgcn_global_load_lds((const gu32*)(vp + 512 + lane * 8), (lu32*)&vls[wv][528], 16, 0, 0);

  short8 qf0 = *(const short8*)(qp + r16 * 64 + quad * 8);
  short8 qf1 = *(const short8*)(qp + r16 * 64 + quad * 8 + 32);
  short8 kf0 = *(const short8*)(kp + r16 * 64 + quad * 8);
  short8 kf1 = *(const short8*)(kp + r16 * 64 + quad * 8 + 32);

  floatx4 sc = {0.f, 0.f, 0.f, 0.f};
  sc = __builtin_amdgcn_mfma_f32_16x16x32_bf16(qf0, kf0, sc, 0, 0, 0);
  sc = __builtin_amdgcn_mfma_f32_16x16x32_bf16(qf1, kf1, sc, 0, 0, 0);

#pragma unroll
  for (int rr = 0; rr < 4; rr++) {
    float s = sc[rr] * 0.125f;
    float m = s;
#pragma unroll
    for (int off = 1; off < 16; off <<= 1) m = fmaxf(m, __shfl_xor(m, off));
    float ex = __expf(s - m);
    float sum = ex;
#pragma unroll
    for (int off = 1; off < 16; off <<= 1) sum += __shfl_xor(sum, off);
    pls[wv][(quad * 4 + rr) * 24 + r16] = f2bf(ex / sum);   // P[h][e]
  }

  __syncthreads();   // covers V DMA completion + cross-lane P visibility

  const short8 zero8 = {0, 0, 0, 0, 0, 0, 0, 0};
  short8 af = zero8;
  short8 bf[4] = {zero8, zero8, zero8, zero8};
  if (quad < 2) {
    af = *(const short8*)&pls[wv][r16 * 24 + quad * 8];
#pragma unroll
    for (int c = 0; c < 4; c++)
#pragma unroll
      for (int jj = 0; jj < 8; jj++)
        bf[c][jj] = (short)vls[wv][quad * 528 + jj * 64 + c * 16 + r16];
  }

  floatx4 ov[4];
#pragma unroll
  for (int c = 0; c < 4; c++) {
    floatx4 z = {0.f, 0.f, 0.f, 0.f};
    ov[c] = __builtin_amdgcn_mfma_f32_16x16x32_bf16(af, bf[c], z, 0, 0, 0);
  }

#pragma unroll
  for (int rr = 0; rr < 4; rr++)
#pragma unroll
    for (int c = 0; c < 4; c++)
      attn[base + (size_t)(quad * 4 + rr) * 64 + c * 16 + r16] = f2bf(ov[c][rr]);
}

extern "C" void kernel_launch(void* const* d_in, const int* in_sizes, int n_in,
                              void* d_out, int out_size, void* d_ws, size_t ws_size,
                              hipStream_t stream) {
  const float* x  = (const float*)d_in[0];
  const float* Wq = (const float*)d_in[1];
  const float* bq = (const float*)d_in[2];
  const float* Wk = (const float*)d_in[3];
  const float* bk = (const float*)d_in[4];
  const float* Wv = (const float*)d_in[5];
  const float* bv = (const float*)d_in[6];
  const float* Wo = (const float*)d_in[7];
  const float* bo = (const float*)d_in[8];

  char* ws = (char*)d_ws;
  unsigned short* xb  = (unsigned short*)ws;                        // 32 MiB
  unsigned short* wt  = (unsigned short*)(ws + (size_t)XELEM * 2);  // 8 MiB
  unsigned short* qkv = wt + 4 * (size_t)WELEM;                     // 96 MiB

  cvt_x_kernel<<<XELEM / 1024, 256, 0, stream>>>(x, xb);
  cvt_w_kernel<<<dim3(16, 16, 4), 256, 0, stream>>>(Wq, Wk, Wv, Wo, wt);
  gemm256<true><<<256, 512, 0, stream>>>(xb, wt, bq, bk, bv, (void*)qkv);
  attn_kernel<<<4096, 256, 0, stream>>>(qkv, qkv);  // attn overwrites q region
  gemm256<false><<<256, 512, 0, stream>>>(qkv, wt, bo, bo, bo, d_out);
}

// Round 4
// 292.019 us; speedup vs baseline: 1.1477x; 1.0019x over previous
//
#include <hip/hip_runtime.h>
#include <stdint.h>

// ---------------------------------------------------------------------------
// LongSelfAttention: x[16384,1024] -> QKV proj -> per-token 16x16 head attn
// -> O proj.
// GEMMs: 256x256 tile, BK=64, 8 waves (2Mx4N), 4 single-barrier phases per
// K-tile with counted vmcnt (T3+T4), LDS XOR-swizzle (T2), setprio (T5),
// XCD swizzle (T1), persistent QKV grid (256 blocks x 3 output tiles).
// This rev: ONE barrier per phase + TRAILING lgkm(0) drain (was 2 barriers +
// leading drain). Compiler now inserts counted per-operand lgkmcnt before
// each MFMA -> intra-wave read||MFMA overlap; no post-MFMA barrier -> cross-
// wave MFMA||read overlap. Hard ordering: every stage->read gated by
// {vmcnt retire pre-BAR, read post-BAR}; every read->overwrite gated by
// {trailing lgkm(0) pre-next-BAR, stage issue post-that-BAR (stage_{p+1}
// regions disjoint from reads_p/reads_{p+1} by construction)}.
// Workspace layout (bytes):
//   [0,            32 MiB) x_bf16           [16384][1024]
//   [32 MiB,       40 MiB) W^T bf16 x4      [4][1024][1024]  (q,k,v,o)
//   [40 MiB,      136 MiB) qkv bf16         [3][16384][1024]  (attn overwrites q)
// ---------------------------------------------------------------------------

typedef __attribute__((ext_vector_type(8))) short short8;
typedef __attribute__((ext_vector_type(4))) float floatx4;
typedef __attribute__((address_space(1))) unsigned int gu32;
typedef __attribute__((address_space(3))) unsigned int lu32;

#define HID 1024
#define MTOK 16384                 // B*L
#define WELEM (HID * HID)          // 1048576
#define XELEM (MTOK * HID)         // 16777216

#define SBAR() __builtin_amdgcn_s_barrier()
// rule #18: pin subsequent code below the wait with a sched_barrier
#define WAITLGKM() do { asm volatile("s_waitcnt lgkmcnt(0)" ::: "memory"); \
                        __builtin_amdgcn_sched_barrier(0); } while (0)
#define VMCNT(n) do { asm volatile("s_waitcnt vmcnt(" #n ")" ::: "memory"); \
                      __builtin_amdgcn_sched_barrier(0); } while (0)

__device__ __forceinline__ unsigned short f2bf(float f) {
  union { float f; uint32_t u; } v; v.f = f;
  uint32_t u = v.u;
  u += 0x7fffu + ((u >> 16) & 1u);   // round-to-nearest-even
  return (unsigned short)(u >> 16);
}

// ---- x fp32 -> bf16, vectorized -------------------------------------------
__global__ __launch_bounds__(256) void cvt_x_kernel(const float* __restrict__ x,
                                                    unsigned short* __restrict__ xb) {
  const int idx = blockIdx.x * 256 + threadIdx.x;
  float4 v = ((const float4*)x)[idx];
  ushort4 o;
  o.x = f2bf(v.x); o.y = f2bf(v.y); o.z = f2bf(v.z); o.w = f2bf(v.w);
  ((ushort4*)xb)[idx] = o;
}

// ---- W [k][n] fp32 -> W^T [n][k] bf16 via 64x64 LDS tile ------------------
__global__ __launch_bounds__(256) void cvt_w_kernel(const float* __restrict__ W0,
                                                    const float* __restrict__ W1,
                                                    const float* __restrict__ W2,
                                                    const float* __restrict__ W3,
                                                    unsigned short* __restrict__ WT) {
  const float* W = (blockIdx.z == 0) ? W0 : (blockIdx.z == 1) ? W1
                   : (blockIdx.z == 2) ? W2 : W3;
  unsigned short* out = WT + (size_t)blockIdx.z * WELEM;
  __shared__ float tile[64][65];
  const int t = threadIdx.x;
  const int n0 = blockIdx.x * 64, k0 = blockIdx.y * 64;
#pragma unroll
  for (int i = 0; i < 4; i++) {
    const int row = i * 16 + (t >> 4);     // k within tile
    const int col = (t & 15) * 4;          // n within tile
    float4 v = *(const float4*)&W[(size_t)(k0 + row) * HID + n0 + col];
    tile[row][col] = v.x; tile[row][col + 1] = v.y;
    tile[row][col + 2] = v.z; tile[row][col + 3] = v.w;
  }
  __syncthreads();
#pragma unroll
  for (int i = 0; i < 4; i++) {
    const int n = i * 16 + (t >> 4);
    const int k = (t & 15) * 4;
    ushort4 o;
    o.x = f2bf(tile[k][n]);     o.y = f2bf(tile[k + 1][n]);
    o.z = f2bf(tile[k + 2][n]); o.w = f2bf(tile[k + 3][n]);
    *(ushort4*)&out[(size_t)(n0 + n) * HID + k0 + k] = o;
  }
}

// ---------------------------------------------------------------------------
// 256x256x(BK=64) NT GEMM, 4 single-barrier phases per K-tile.
// Phase p = { stage ; ds_reads ; [vmcnt] ; SBAR ; setprio1 ; MFMA ; setprio0 ;
//             lgkm(0) }.
// Reads: P1 A-lo(8), P2 b23(4), P3 A-hi(8), P4 b01-next(4).
// Stage rotation: P1 A0(t+1), P2 A1(t+1), P3 B0(t+2), P4 B1(t+2).
// Waits: vmcnt(6) @P3 pre-BAR (retires {B0,B1}(t+1) for P4's reads),
//        vmcnt(4) @P4 pre-BAR (retires {A0,A1}(t+1); {B0,B1}(t+2) in flight).
// Race audit (single-barrier): stage_p and stage_{p+1} regions are disjoint
// from reads_p and reads_{p+1} (A vs B halves / alternating buffers); the
// closest overwrite pair is stage_{p+2} vs reads_p (2 barriers apart, and
// reads_p are lgkm-drained by every wave before it can arrive at BAR(p+1),
// which must happen before any wave issues stage_{p+2}).
// Zigzag quadrants: Q0=Alo*b01, Q1=Alo*b23, Q2=Ahi*b23, Q3=Ahi*b01.
// Persistent: QKV runs R=3 output tiles per block (same m-band, Bg+=WELEM);
// next tile's prologue stages are issued before the epilogue stores.
// ---------------------------------------------------------------------------
template <bool QKV>
__global__ __launch_bounds__(512, 2) void gemm256(
    const unsigned short* __restrict__ A,     // [MTOK][HID] bf16
    const unsigned short* __restrict__ BTb,   // base of W^T array
    const float* __restrict__ b0, const float* __restrict__ b1,
    const float* __restrict__ b2,
    void* __restrict__ Cv)
{
  __shared__ short8 smem_[131072 / 16];      // 128 KiB
  char* smem = (char*)smem_;

  constexpr int R = QKV ? 3 : 1;
  const int bid = blockIdx.x;
  const int xcd = bid & 7;
  const int j = bid >> 3;                    // 0..31
  const int nb0 = j >> 3;                    // 0..3
  const int mb = xcd * 8 + (j & 7);          // 0..63 (m-band per XCD, fixed)
  const int m0 = mb * 256;
  const int cb = nb0 * 256;                  // output col base (per-matrix)

  const unsigned short* BT0 = QKV ? BTb : (BTb + (size_t)3 * WELEM);

  const int t_ = threadIdx.x;
  const int wv = t_ >> 6, lane = t_ & 63;
  const int quad = lane >> 4, r16 = lane & 15;
  const int wm = wv >> 2, wn = wv & 3;

  // staging source (per-lane; k-chunk pre-permuted to compensate swizzle)
  const int srow = wv * 16 + (lane >> 2);
  const int scol = ((lane & 3) ^ ((lane >> 3) & 3)) * 8;
  const unsigned short* Ag = A + (size_t)(m0 + srow) * HID + scol;
  const unsigned short* Bg = BT0 + (size_t)(cb + srow) * HID + scol;

  // ds_read bases (swizzled): byte = base + ks*8192 + frag*1024
  const int qsw = (quad ^ ((r16 >> 1) & 3)) << 4;
  const char* Ard = smem + wm * 16384 + r16 * 64 + qsw;
  const char* Brd = smem + 32768 + (wn >> 1) * 16384 + ((wn & 1) * 64 + r16) * 64 + qsw;

  floatx4 acc[8][4] = {};

  // stage half h of K-tile tt into buffer tt&1 (LDS dest linear, rule #21)
  auto stageA = [&](int h, int tt) {
    const unsigned short* s = Ag + (size_t)h * 128 * HID + tt * 64;
    char* d = smem + ((tt & 1) << 16) + h * 16384 + wv * 1024;
    __builtin_amdgcn_global_load_lds((const gu32*)s,        (lu32*)d,          16, 0, 0);
    __builtin_amdgcn_global_load_lds((const gu32*)(s + 32), (lu32*)(d + 8192), 16, 0, 0);
  };
  auto stageB = [&](int h, int tt) {
    const unsigned short* s = Bg + (size_t)h * 128 * HID + tt * 64;
    char* d = smem + ((tt & 1) << 16) + 32768 + h * 16384 + wv * 1024;
    __builtin_amdgcn_global_load_lds((const gu32*)s,        (lu32*)d,          16, 0, 0);
    __builtin_amdgcn_global_load_lds((const gu32*)(s + 32), (lu32*)(d + 8192), 16, 0, 0);
  };

  const int NT = HID / 64;                   // 16 K-tiles (even)

  short8 a[4][2];                            // A-lo then A-hi (reused)
  short8 b23[2][2];                          // wave n-frags 2,3 (per tile)
  short8 bA[2][2], bB[2][2];                 // b01 double-buffer across tiles

  // one K-tile: bufb = (t&1)<<16, othb = buffer of t+1; bc = b01 of t,
  // bn = b01 of t+1 (read in P4).
  auto TILE = [&](int t, int bufb, int othb, short8 (&bc)[2][2], short8 (&bn)[2][2]) {
    // ---- P1: stage A0(t+1); read A-lo(8); BAR; Q0 = Alo x b01 -------------
    if (t + 1 < NT) stageA(0, t + 1);
#pragma unroll
    for (int ks = 0; ks < 2; ++ks)
#pragma unroll
      for (int mi = 0; mi < 4; ++mi)
        a[mi][ks] = *(const short8*)(Ard + bufb + ks * 8192 + mi * 1024);
    SBAR();
    __builtin_amdgcn_s_setprio(1);
#pragma unroll
    for (int ks = 0; ks < 2; ++ks)
#pragma unroll
      for (int mi = 0; mi < 4; ++mi)
#pragma unroll
        for (int ni = 0; ni < 2; ++ni)
          acc[mi][ni] = __builtin_amdgcn_mfma_f32_16x16x32_bf16(a[mi][ks], bc[ni][ks], acc[mi][ni], 0, 0, 0);
    __builtin_amdgcn_s_setprio(0);
    WAITLGKM();

    // ---- P2: stage A1(t+1); read b23(4); BAR; Q1 = Alo x b23 --------------
    if (t + 1 < NT) stageA(1, t + 1);
#pragma unroll
    for (int ks = 0; ks < 2; ++ks)
#pragma unroll
      for (int ni = 0; ni < 2; ++ni)
        b23[ni][ks] = *(const short8*)(Brd + bufb + ks * 8192 + (2 + ni) * 1024);
    SBAR();
    __builtin_amdgcn_s_setprio(1);
#pragma unroll
    for (int ks = 0; ks < 2; ++ks)
#pragma unroll
      for (int mi = 0; mi < 4; ++mi)
#pragma unroll
        for (int ni = 0; ni < 2; ++ni)
          acc[mi][2 + ni] = __builtin_amdgcn_mfma_f32_16x16x32_bf16(a[mi][ks], b23[ni][ks], acc[mi][2 + ni], 0, 0, 0);
    __builtin_amdgcn_s_setprio(0);
    WAITLGKM();

    // ---- P3: stage B0(t+2); read A-hi(8); vmcnt; BAR; Q2 = Ahi x b23 ------
    if (t + 2 < NT) stageB(0, t + 2);
#pragma unroll
    for (int ks = 0; ks < 2; ++ks)
#pragma unroll
      for (int mi = 0; mi < 4; ++mi)
        a[mi][ks] = *(const short8*)(Ard + bufb + ks * 8192 + (4 + mi) * 1024);
    // retire {B0,B1}(t+1) before the barrier; P4 reads them after it
    if (t + 2 < NT)      { VMCNT(6); }
    else if (t + 1 < NT) { VMCNT(4); }
    SBAR();
    __builtin_amdgcn_s_setprio(1);
#pragma unroll
    for (int ks = 0; ks < 2; ++ks)
#pragma unroll
      for (int mi = 0; mi < 4; ++mi)
#pragma unroll
        for (int ni = 0; ni < 2; ++ni)
          acc[4 + mi][2 + ni] = __builtin_amdgcn_mfma_f32_16x16x32_bf16(a[mi][ks], b23[ni][ks], acc[4 + mi][2 + ni], 0, 0, 0);
    __builtin_amdgcn_s_setprio(0);
    WAITLGKM();

    // ---- P4: stage B1(t+2); read b01-next(4); vmcnt; BAR; Q3 = Ahi x b01 --
    if (t + 2 < NT) stageB(1, t + 2);
    if (t + 1 < NT) {
#pragma unroll
      for (int ks = 0; ks < 2; ++ks)
#pragma unroll
        for (int ni = 0; ni < 2; ++ni)
          bn[ni][ks] = *(const short8*)(Brd + othb + ks * 8192 + ni * 1024);
    }
    // retire {A0,A1}(t+1); leave {B0,B1}(t+2) in flight across the boundary
    if (t + 2 < NT)      { VMCNT(4); }
    else if (t + 1 < NT) { VMCNT(0); }
    SBAR();
    __builtin_amdgcn_s_setprio(1);
#pragma unroll
    for (int ks = 0; ks < 2; ++ks)
#pragma unroll
      for (int mi = 0; mi < 4; ++mi)
#pragma unroll
        for (int ni = 0; ni < 2; ++ni)
          acc[4 + mi][ni] = __builtin_amdgcn_mfma_f32_16x16x32_bf16(a[mi][ks], bc[ni][ks], acc[4 + mi][ni], 0, 0, 0);
    __builtin_amdgcn_s_setprio(0);
    WAITLGKM();   // drains bn reads too -> hard ordering vs later stages
  };

  // prologue for output-tile 0: tile0 fully + {B0,B1}(1); leave B(1) in flight
  stageA(0, 0); stageA(1, 0); stageB(0, 0); stageB(1, 0);
  stageB(0, 1); stageB(1, 1);
  VMCNT(4);
  SBAR();
#pragma unroll
  for (int ks = 0; ks < 2; ++ks)
#pragma unroll
    for (int ni = 0; ni < 2; ++ni)
      bA[ni][ks] = *(const short8*)(Brd + ks * 8192 + ni * 1024);

  for (int r = 0; r < R; ++r) {
    for (int t = 0; t < NT; t += 2) {
      TILE(t,     0,       0x10000, bA, bB);
      TILE(t + 1, 0x10000, 0,       bB, bA);
    }

    // issue next output-tile's prologue stages before the epilogue stores
    if (r + 1 < R) {
      Bg += WELEM;                           // next weight matrix (z = r+1)
      stageA(0, 0); stageA(1, 0); stageB(0, 0); stageB(1, 0);
      stageB(0, 1); stageB(1, 1);
    }

    // epilogue: C/D layout col=lane&15, row=quad*4+reg (measured m89/m91)
    {
      const float* bias = QKV ? ((r == 0) ? b0 : ((r == 1) ? b1 : b2)) : b0;
      float bvv[4];
#pragma unroll
      for (int ni = 0; ni < 4; ++ni) bvv[ni] = bias[cb + wn * 64 + ni * 16 + r16];

      const int row0 = m0 + wm * 128 + quad * 4;
      unsigned short* outb = (unsigned short*)Cv + (size_t)r * XELEM;
      float* outf = (float*)Cv;
#pragma unroll
      for (int mi = 0; mi < 8; ++mi) {
#pragma unroll
        for (int rr = 0; rr < 4; ++rr) {
          const size_t roff = (size_t)(row0 + mi * 16 + rr) * HID + cb + wn * 64 + r16;
#pragma unroll
          for (int ni = 0; ni < 4; ++ni) {
            const float val = acc[mi][ni][rr] + bvv[ni];
            if constexpr (QKV) outb[roff + ni * 16] = f2bf(val);
            else               outf[roff + ni * 16] = val;
          }
        }
      }
    }

    if (r + 1 < R) {
      // zero acc, drain stages (+stores), re-read b01(0) for next tile
#pragma unroll
      for (int mi = 0; mi < 8; ++mi)
#pragma unroll
        for (int ni = 0; ni < 4; ++ni)
          acc[mi][ni] = floatx4{0.f, 0.f, 0.f, 0.f};
      VMCNT(0);
      SBAR();
#pragma unroll
      for (int ks = 0; ks < 2; ++ks)
#pragma unroll
        for (int ni = 0; ni < 2; ++ni)
          bA[ni][ks] = *(const short8*)(Brd + ks * 8192 + ni * 1024);
    }
  }
}

// ---- per-token head attention: one wave per token, all-MFMA ---------------
__global__ __launch_bounds__(256) void attn_kernel(const unsigned short* qkv,
                                                   unsigned short* attn) {
  __shared__ unsigned short vls[4][1056];    // per wave: rows0-7 @0, rows8-15 @528
  __shared__ unsigned short pls[4][16 * 24]; // P bf16, stride 24 ushorts (48B)

  const int t = threadIdx.x;
  const int wv = t >> 6, lane = t & 63;
  const int quad = lane >> 4, r16 = lane & 15;
  const size_t base = ((size_t)blockIdx.x * 4 + wv) * HID;
  const unsigned short* qp = qkv + base;                     // q[16][64]
  const unsigned short* kp = qkv + (size_t)XELEM + base;     // k[16][64]
  const unsigned short* vp = qkv + 2 * (size_t)XELEM + base; // v[16][64]

  __builtin_amdgcn_global_load_lds((const gu32*)(vp + lane * 8),       (lu32*)&vls[wv][0],   16, 0, 0);
  __builtin_amdgcn_global_load_lds((const gu32*)(vp + 512 + lane * 8), (lu32*)&vls[wv][528], 16, 0, 0);

  short8 qf0 = *(const short8*)(qp + r16 * 64 + quad * 8);
  short8 qf1 = *(const short8*)(qp + r16 * 64 + quad * 8 + 32);
  short8 kf0 = *(const short8*)(kp + r16 * 64 + quad * 8);
  short8 kf1 = *(const short8*)(kp + r16 * 64 + quad * 8 + 32);

  floatx4 sc = {0.f, 0.f, 0.f, 0.f};
  sc = __builtin_amdgcn_mfma_f32_16x16x32_bf16(qf0, kf0, sc, 0, 0, 0);
  sc = __builtin_amdgcn_mfma_f32_16x16x32_bf16(qf1, kf1, sc, 0, 0, 0);

#pragma unroll
  for (int rr = 0; rr < 4; rr++) {
    float s = sc[rr] * 0.125f;
    float m = s;
#pragma unroll
    for (int off = 1; off < 16; off <<= 1) m = fmaxf(m, __shfl_xor(m, off));
    float ex = __expf(s - m);
    float sum = ex;
#pragma unroll
    for (int off = 1; off < 16; off <<= 1) sum += __shfl_xor(sum, off);
    pls[wv][(quad * 4 + rr) * 24 + r16] = f2bf(ex / sum);   // P[h][e]
  }

  __syncthreads();   // covers V DMA completion + cross-lane P visibility

  const short8 zero8 = {0, 0, 0, 0, 0, 0, 0, 0};
  short8 af = zero8;
  short8 bf[4] = {zero8, zero8, zero8, zero8};
  if (quad < 2) {
    af = *(const short8*)&pls[wv][r16 * 24 + quad * 8];
#pragma unroll
    for (int c = 0; c < 4; c++)
#pragma unroll
      for (int jj = 0; jj < 8; jj++)
        bf[c][jj] = (short)vls[wv][quad * 528 + jj * 64 + c * 16 + r16];
  }

  floatx4 ov[4];
#pragma unroll
  for (int c = 0; c < 4; c++) {
    floatx4 z = {0.f, 0.f, 0.f, 0.f};
    ov[c] = __builtin_amdgcn_mfma_f32_16x16x32_bf16(af, bf[c], z, 0, 0, 0);
  }

#pragma unroll
  for (int rr = 0; rr < 4; rr++)
#pragma unroll
    for (int c = 0; c < 4; c++)
      attn[base + (size_t)(quad * 4 + rr) * 64 + c * 16 + r16] = f2bf(ov[c][rr]);
}

extern "C" void kernel_launch(void* const* d_in, const int* in_sizes, int n_in,
                              void* d_out, int out_size, void* d_ws, size_t ws_size,
                              hipStream_t stream) {
  const float* x  = (const float*)d_in[0];
  const float* Wq = (const float*)d_in[1];
  const float* bq = (const float*)d_in[2];
  const float* Wk = (const float*)d_in[3];
  const float* bk = (const float*)d_in[4];
  const float* Wv = (const float*)d_in[5];
  const float* bv = (const float*)d_in[6];
  const float* Wo = (const float*)d_in[7];
  const float* bo = (const float*)d_in[8];

  char* ws = (char*)d_ws;
  unsigned short* xb  = (unsigned short*)ws;                        // 32 MiB
  unsigned short* wt  = (unsigned short*)(ws + (size_t)XELEM * 2);  // 8 MiB
  unsigned short* qkv = wt + 4 * (size_t)WELEM;                     // 96 MiB

  cvt_x_kernel<<<XELEM / 1024, 256, 0, stream>>>(x, xb);
  cvt_w_kernel<<<dim3(16, 16, 4), 256, 0, stream>>>(Wq, Wk, Wv, Wo, wt);
  gemm256<true><<<256, 512, 0, stream>>>(xb, wt, bq, bk, bv, (void*)qkv);
  attn_kernel<<<4096, 256, 0, stream>>>(qkv, qkv);  // attn overwrites q region
  gemm256<false><<<256, 512, 0, stream>>>(qkv, wt, bo, bo, bo, d_out);
}

// Round 5
// 287.217 us; speedup vs baseline: 1.1668x; 1.0167x over previous
//
#include <hip/hip_runtime.h>
#include <stdint.h>

// ---------------------------------------------------------------------------
// LongSelfAttention: x[16384,1024] -> QKV proj -> per-token 16x16 head attn
// -> O proj.
// GEMMs: 256x256 tile, BK=64, 8 waves (2Mx4N), 4 single-barrier phases per
// K-tile. THIS REV: register read-ahead — each phase's ds_reads feed a LATER
// phase's MFMA, so the LDS burst of phase p is served under the MFMAs of
// phase p (true LDS||MFMA overlap; round-4 counters proved they were serial:
// 2483 cy MFMA + 2600 cy LDS = 5080 cy/tile measured).
//   P1: reads b01(t)+b23(t)   -> Q0 (b01 same-phase short wait), Q1
//   P2: reads Ahi(t)          -> Q2, Q3
//   P3: reads Alo(t+1) mi0-1  -> next tile's Q0/Q1
//   P4: reads Alo(t+1) mi2-3
// Stage rotation (all of tile t+1): P1:A0, P2:A1, P3:B0, P4:B1.
// Counted-vmcnt ledger (2 instr per stage call):
//   P1: VMCNT(2)  retires {B0,B1}(t) [+A1(t)] for b01/b23/Ahi reads
//   P3: VMCNT(4)  retires A0(t+1) for the cross-buffer Alo reads
//   last tile P1: VMCNT(0). Never 0 mid-loop otherwise.
// WAR audit: every LDS overwrite is >=2 barriers after its last reader's
// end-phase lgkm(0) drain. LDS XOR-swizzle (T2) unchanged; setprio (T5),
// XCD swizzle (T1), persistent QKV grid (256 blocks x 3 matrices) unchanged.
// Workspace layout (bytes):
//   [0,            32 MiB) x_bf16           [16384][1024]
//   [32 MiB,       40 MiB) W^T bf16 x4      [4][1024][1024]  (q,k,v,o)
//   [40 MiB,      136 MiB) qkv bf16         [3][16384][1024]  (attn overwrites q)
// ---------------------------------------------------------------------------

typedef __attribute__((ext_vector_type(8))) short short8;
typedef __attribute__((ext_vector_type(4))) float floatx4;
typedef __attribute__((address_space(1))) unsigned int gu32;
typedef __attribute__((address_space(3))) unsigned int lu32;

#define HID 1024
#define MTOK 16384                 // B*L
#define WELEM (HID * HID)          // 1048576
#define XELEM (MTOK * HID)         // 16777216

#define SBAR() __builtin_amdgcn_s_barrier()
// rule #18: pin subsequent code below the wait with a sched_barrier
#define WAITLGKM() do { asm volatile("s_waitcnt lgkmcnt(0)" ::: "memory"); \
                        __builtin_amdgcn_sched_barrier(0); } while (0)
#define VMCNT(n) do { asm volatile("s_waitcnt vmcnt(" #n ")" ::: "memory"); \
                      __builtin_amdgcn_sched_barrier(0); } while (0)

__device__ __forceinline__ unsigned short f2bf(float f) {
  union { float f; uint32_t u; } v; v.f = f;
  uint32_t u = v.u;
  u += 0x7fffu + ((u >> 16) & 1u);   // round-to-nearest-even
  return (unsigned short)(u >> 16);
}

// ---- x fp32 -> bf16, vectorized -------------------------------------------
__global__ __launch_bounds__(256) void cvt_x_kernel(const float* __restrict__ x,
                                                    unsigned short* __restrict__ xb) {
  const int idx = blockIdx.x * 256 + threadIdx.x;
  float4 v = ((const float4*)x)[idx];
  ushort4 o;
  o.x = f2bf(v.x); o.y = f2bf(v.y); o.z = f2bf(v.z); o.w = f2bf(v.w);
  ((ushort4*)xb)[idx] = o;
}

// ---- W [k][n] fp32 -> W^T [n][k] bf16 via 64x64 LDS tile ------------------
__global__ __launch_bounds__(256) void cvt_w_kernel(const float* __restrict__ W0,
                                                    const float* __restrict__ W1,
                                                    const float* __restrict__ W2,
                                                    const float* __restrict__ W3,
                                                    unsigned short* __restrict__ WT) {
  const float* W = (blockIdx.z == 0) ? W0 : (blockIdx.z == 1) ? W1
                   : (blockIdx.z == 2) ? W2 : W3;
  unsigned short* out = WT + (size_t)blockIdx.z * WELEM;
  __shared__ float tile[64][65];
  const int t = threadIdx.x;
  const int n0 = blockIdx.x * 64, k0 = blockIdx.y * 64;
#pragma unroll
  for (int i = 0; i < 4; i++) {
    const int row = i * 16 + (t >> 4);     // k within tile
    const int col = (t & 15) * 4;          // n within tile
    float4 v = *(const float4*)&W[(size_t)(k0 + row) * HID + n0 + col];
    tile[row][col] = v.x; tile[row][col + 1] = v.y;
    tile[row][col + 2] = v.z; tile[row][col + 3] = v.w;
  }
  __syncthreads();
#pragma unroll
  for (int i = 0; i < 4; i++) {
    const int n = i * 16 + (t >> 4);
    const int k = (t & 15) * 4;
    ushort4 o;
    o.x = f2bf(tile[k][n]);     o.y = f2bf(tile[k + 1][n]);
    o.z = f2bf(tile[k + 2][n]); o.w = f2bf(tile[k + 3][n]);
    *(ushort4*)&out[(size_t)(n0 + n) * HID + k0 + k] = o;
  }
}

// ---------------------------------------------------------------------------
// 256x256x(BK=64) NT GEMM with register read-ahead (see header comment).
// ---------------------------------------------------------------------------
template <bool QKV>
__global__ __launch_bounds__(512, 2) void gemm256(
    const unsigned short* __restrict__ A,     // [MTOK][HID] bf16
    const unsigned short* __restrict__ BTb,   // base of W^T array
    const float* __restrict__ b0, const float* __restrict__ b1,
    const float* __restrict__ b2,
    void* __restrict__ Cv)
{
  __shared__ short8 smem_[131072 / 16];      // 128 KiB
  char* smem = (char*)smem_;

  constexpr int R = QKV ? 3 : 1;
  const int bid = blockIdx.x;
  const int xcd = bid & 7;
  const int j = bid >> 3;                    // 0..31
  const int nb0 = j >> 3;                    // 0..3
  const int mb = xcd * 8 + (j & 7);          // 0..63 (m-band per XCD, fixed)
  const int m0 = mb * 256;
  const int cb = nb0 * 256;                  // output col base (per-matrix)

  const unsigned short* BT0 = QKV ? BTb : (BTb + (size_t)3 * WELEM);

  const int t_ = threadIdx.x;
  const int wv = t_ >> 6, lane = t_ & 63;
  const int quad = lane >> 4, r16 = lane & 15;
  const int wm = wv >> 2, wn = wv & 3;

  // staging source (per-lane; k-chunk pre-permuted to compensate swizzle)
  const int srow = wv * 16 + (lane >> 2);
  const int scol = ((lane & 3) ^ ((lane >> 3) & 3)) * 8;
  const unsigned short* Ag = A + (size_t)(m0 + srow) * HID + scol;
  const unsigned short* Bg = BT0 + (size_t)(cb + srow) * HID + scol;

  // ds_read bases (swizzled): byte = base + ks*8192 + frag*1024
  const int qsw = (quad ^ ((r16 >> 1) & 3)) << 4;
  const char* Ard = smem + wm * 16384 + r16 * 64 + qsw;
  const char* Brd = smem + 32768 + (wn >> 1) * 16384 + ((wn & 1) * 64 + r16) * 64 + qsw;

  floatx4 acc[8][4] = {};

  // stage half h of K-tile tt into buffer tt&1 (LDS dest linear, rule #21)
  auto stageA = [&](int h, int tt) {
    const unsigned short* s = Ag + (size_t)h * 128 * HID + tt * 64;
    char* d = smem + ((tt & 1) << 16) + h * 16384 + wv * 1024;
    __builtin_amdgcn_global_load_lds((const gu32*)s,        (lu32*)d,          16, 0, 0);
    __builtin_amdgcn_global_load_lds((const gu32*)(s + 32), (lu32*)(d + 8192), 16, 0, 0);
  };
  auto stageB = [&](int h, int tt) {
    const unsigned short* s = Bg + (size_t)h * 128 * HID + tt * 64;
    char* d = smem + ((tt & 1) << 16) + 32768 + h * 16384 + wv * 1024;
    __builtin_amdgcn_global_load_lds((const gu32*)s,        (lu32*)d,          16, 0, 0);
    __builtin_amdgcn_global_load_lds((const gu32*)(s + 32), (lu32*)(d + 8192), 16, 0, 0);
  };

  const int NT = HID / 64;                   // 16 K-tiles (even)

  short8 alo[4][2], ahi[4][2];               // A fragments (read-ahead)
  short8 b01[2][2], b23[2][2];               // B fragments

  // prologue: stage tile 0, drain, read Alo(0)
  stageA(0, 0); stageA(1, 0); stageB(0, 0); stageB(1, 0);
  VMCNT(0);
  SBAR();
#pragma unroll
  for (int ks = 0; ks < 2; ++ks)
#pragma unroll
    for (int mi = 0; mi < 4; ++mi)
      alo[mi][ks] = *(const short8*)(Ard + ks * 8192 + mi * 1024);

  for (int r = 0; r < R; ++r) {
    for (int t = 0; t < NT; ++t) {
      const int bufb = (t & 1) << 16;
      const int nxtb = bufb ^ 0x10000;
      const bool more = (t + 1 < NT);

      // ---- P1: stage A0(t+1); gate B(t); read b01+b23(t); Q0=Alo*b01 ------
      if (more) { stageA(0, t + 1); VMCNT(2); } else { VMCNT(0); }
      SBAR();
#pragma unroll
      for (int ks = 0; ks < 2; ++ks)
#pragma unroll
        for (int ni = 0; ni < 2; ++ni)
          b01[ni][ks] = *(const short8*)(Brd + bufb + ks * 8192 + ni * 1024);
#pragma unroll
      for (int ks = 0; ks < 2; ++ks)
#pragma unroll
        for (int ni = 0; ni < 2; ++ni)
          b23[ni][ks] = *(const short8*)(Brd + bufb + ks * 8192 + (2 + ni) * 1024);
      __builtin_amdgcn_s_setprio(1);
#pragma unroll
      for (int ks = 0; ks < 2; ++ks)
#pragma unroll
        for (int mi = 0; mi < 4; ++mi)
#pragma unroll
          for (int ni = 0; ni < 2; ++ni)
            acc[mi][ni] = __builtin_amdgcn_mfma_f32_16x16x32_bf16(alo[mi][ks], b01[ni][ks], acc[mi][ni], 0, 0, 0);
      __builtin_amdgcn_s_setprio(0);
      WAITLGKM();

      // ---- P2: stage A1(t+1); read Ahi(t); Q1=Alo*b23 ---------------------
      if (more) stageA(1, t + 1);
      SBAR();
#pragma unroll
      for (int ks = 0; ks < 2; ++ks)
#pragma unroll
        for (int mi = 0; mi < 4; ++mi)
          ahi[mi][ks] = *(const short8*)(Ard + bufb + ks * 8192 + (4 + mi) * 1024);
      __builtin_amdgcn_s_setprio(1);
#pragma unroll
      for (int ks = 0; ks < 2; ++ks)
#pragma unroll
        for (int mi = 0; mi < 4; ++mi)
#pragma unroll
          for (int ni = 0; ni < 2; ++ni)
            acc[mi][2 + ni] = __builtin_amdgcn_mfma_f32_16x16x32_bf16(alo[mi][ks], b23[ni][ks], acc[mi][2 + ni], 0, 0, 0);
      __builtin_amdgcn_s_setprio(0);
      WAITLGKM();

      // ---- P3: stage B0(t+1); gate A0(t+1); read Alo(t+1) mi0-1; Q2 -------
      if (more) { stageB(0, t + 1); VMCNT(4); }
      SBAR();
      if (more) {
#pragma unroll
        for (int ks = 0; ks < 2; ++ks)
#pragma unroll
          for (int mi = 0; mi < 2; ++mi)
            alo[mi][ks] = *(const short8*)(Ard + nxtb + ks * 8192 + mi * 1024);
      }
      __builtin_amdgcn_s_setprio(1);
#pragma unroll
      for (int ks = 0; ks < 2; ++ks)
#pragma unroll
        for (int mi = 0; mi < 4; ++mi)
#pragma unroll
          for (int ni = 0; ni < 2; ++ni)
            acc[4 + mi][2 + ni] = __builtin_amdgcn_mfma_f32_16x16x32_bf16(ahi[mi][ks], b23[ni][ks], acc[4 + mi][2 + ni], 0, 0, 0);
      __builtin_amdgcn_s_setprio(0);
      WAITLGKM();

      // ---- P4: stage B1(t+1); read Alo(t+1) mi2-3; Q3=Ahi*b01 -------------
      if (more) stageB(1, t + 1);
      SBAR();
      if (more) {
#pragma unroll
        for (int ks = 0; ks < 2; ++ks)
#pragma unroll
          for (int mi = 2; mi < 4; ++mi)
            alo[mi][ks] = *(const short8*)(Ard + nxtb + ks * 8192 + mi * 1024);
      }
      __builtin_amdgcn_s_setprio(1);
#pragma unroll
      for (int ks = 0; ks < 2; ++ks)
#pragma unroll
        for (int mi = 0; mi < 4; ++mi)
#pragma unroll
          for (int ni = 0; ni < 2; ++ni)
            acc[4 + mi][ni] = __builtin_amdgcn_mfma_f32_16x16x32_bf16(ahi[mi][ks], b01[ni][ks], acc[4 + mi][ni], 0, 0, 0);
      __builtin_amdgcn_s_setprio(0);
      WAITLGKM();
    }

    // issue next matrix's tile-0 stages before the epilogue stores
    if (r + 1 < R) {
      Bg += WELEM;                           // next weight matrix (z = r+1)
      stageA(0, 0); stageA(1, 0); stageB(0, 0); stageB(1, 0);
    }

    // epilogue: C/D layout col=lane&15, row=quad*4+reg (measured m89/m91)
    {
      const float* bias = QKV ? ((r == 0) ? b0 : ((r == 1) ? b1 : b2)) : b0;
      float bvv[4];
#pragma unroll
      for (int ni = 0; ni < 4; ++ni) bvv[ni] = bias[cb + wn * 64 + ni * 16 + r16];

      const int row0 = m0 + wm * 128 + quad * 4;
      unsigned short* outb = (unsigned short*)Cv + (size_t)r * XELEM;
      float* outf = (float*)Cv;
#pragma unroll
      for (int mi = 0; mi < 8; ++mi) {
#pragma unroll
        for (int rr = 0; rr < 4; ++rr) {
          const size_t roff = (size_t)(row0 + mi * 16 + rr) * HID + cb + wn * 64 + r16;
#pragma unroll
          for (int ni = 0; ni < 4; ++ni) {
            const float val = acc[mi][ni][rr] + bvv[ni];
            if constexpr (QKV) outb[roff + ni * 16] = f2bf(val);
            else               outf[roff + ni * 16] = val;
          }
        }
      }
    }

    if (r + 1 < R) {
      // zero acc, drain stages+stores, read Alo(0) of next matrix (buf0)
#pragma unroll
      for (int mi = 0; mi < 8; ++mi)
#pragma unroll
        for (int ni = 0; ni < 4; ++ni)
          acc[mi][ni] = floatx4{0.f, 0.f, 0.f, 0.f};
      VMCNT(0);
      SBAR();
#pragma unroll
      for (int ks = 0; ks < 2; ++ks)
#pragma unroll
        for (int mi = 0; mi < 4; ++mi)
          alo[mi][ks] = *(const short8*)(Ard + ks * 8192 + mi * 1024);
    }
  }
}

// ---- per-token head attention: one wave per token, all-MFMA ---------------
__global__ __launch_bounds__(256) void attn_kernel(const unsigned short* qkv,
                                                   unsigned short* attn) {
  __shared__ unsigned short vls[4][1056];    // per wave: rows0-7 @0, rows8-15 @528
  __shared__ unsigned short pls[4][16 * 24]; // P bf16, stride 24 ushorts (48B)

  const int t = threadIdx.x;
  const int wv = t >> 6, lane = t & 63;
  const int quad = lane >> 4, r16 = lane & 15;
  const size_t base = ((size_t)blockIdx.x * 4 + wv) * HID;
  const unsigned short* qp = qkv + base;                     // q[16][64]
  const unsigned short* kp = qkv + (size_t)XELEM + base;     // k[16][64]
  const unsigned short* vp = qkv + 2 * (size_t)XELEM + base; // v[16][64]

  __builtin_amdgcn_global_load_lds((const gu32*)(vp + lane * 8),       (lu32*)&vls[wv][0],   16, 0, 0);
  __builtin_amdgcn_global_load_lds((const gu32*)(vp + 512 + lane * 8), (lu32*)&vls[wv][528], 16, 0, 0);

  short8 qf0 = *(const short8*)(qp + r16 * 64 + quad * 8);
  short8 qf1 = *(const short8*)(qp + r16 * 64 + quad * 8 + 32);
  short8 kf0 = *(const short8*)(kp + r16 * 64 + quad * 8);
  short8 kf1 = *(const short8*)(kp + r16 * 64 + quad * 8 + 32);

  floatx4 sc = {0.f, 0.f, 0.f, 0.f};
  sc = __builtin_amdgcn_mfma_f32_16x16x32_bf16(qf0, kf0, sc, 0, 0, 0);
  sc = __builtin_amdgcn_mfma_f32_16x16x32_bf16(qf1, kf1, sc, 0, 0, 0);

#pragma unroll
  for (int rr = 0; rr < 4; rr++) {
    float s = sc[rr] * 0.125f;
    float m = s;
#pragma unroll
    for (int off = 1; off < 16; off <<= 1) m = fmaxf(m, __shfl_xor(m, off));
    float ex = __expf(s - m);
    float sum = ex;
#pragma unroll
    for (int off = 1; off < 16; off <<= 1) sum += __shfl_xor(sum, off);
    pls[wv][(quad * 4 + rr) * 24 + r16] = f2bf(ex / sum);   // P[h][e]
  }

  __syncthreads();   // covers V DMA completion + cross-lane P visibility

  const short8 zero8 = {0, 0, 0, 0, 0, 0, 0, 0};
  short8 af = zero8;
  short8 bf[4] = {zero8, zero8, zero8, zero8};
  if (quad < 2) {
    af = *(const short8*)&pls[wv][r16 * 24 + quad * 8];
#pragma unroll
    for (int c = 0; c < 4; c++)
#pragma unroll
      for (int jj = 0; jj < 8; jj++)
        bf[c][jj] = (short)vls[wv][quad * 528 + jj * 64 + c * 16 + r16];
  }

  floatx4 ov[4];
#pragma unroll
  for (int c = 0; c < 4; c++) {
    floatx4 z = {0.f, 0.f, 0.f, 0.f};
    ov[c] = __builtin_amdgcn_mfma_f32_16x16x32_bf16(af, bf[c], z, 0, 0, 0);
  }

#pragma unroll
  for (int rr = 0; rr < 4; rr++)
#pragma unroll
    for (int c = 0; c < 4; c++)
      attn[base + (size_t)(quad * 4 + rr) * 64 + c * 16 + r16] = f2bf(ov[c][rr]);
}

extern "C" void kernel_launch(void* const* d_in, const int* in_sizes, int n_in,
                              void* d_out, int out_size, void* d_ws, size_t ws_size,
                              hipStream_t stream) {
  const float* x  = (const float*)d_in[0];
  const float* Wq = (const float*)d_in[1];
  const float* bq = (const float*)d_in[2];
  const float* Wk = (const float*)d_in[3];
  const float* bk = (const float*)d_in[4];
  const float* Wv = (const float*)d_in[5];
  const float* bv = (const float*)d_in[6];
  const float* Wo = (const float*)d_in[7];
  const float* bo = (const float*)d_in[8];

  char* ws = (char*)d_ws;
  unsigned short* xb  = (unsigned short*)ws;                        // 32 MiB
  unsigned short* wt  = (unsigned short*)(ws + (size_t)XELEM * 2);  // 8 MiB
  unsigned short* qkv = wt + 4 * (size_t)WELEM;                     // 96 MiB

  cvt_x_kernel<<<XELEM / 1024, 256, 0, stream>>>(x, xb);
  cvt_w_kernel<<<dim3(16, 16, 4), 256, 0, stream>>>(Wq, Wk, Wv, Wo, wt);
  gemm256<true><<<256, 512, 0, stream>>>(xb, wt, bq, bk, bv, (void*)qkv);
  attn_kernel<<<4096, 256, 0, stream>>>(qkv, qkv);  // attn overwrites q region
  gemm256<false><<<256, 512, 0, stream>>>(qkv, wt, bo, bo, bo, d_out);
}